// Round 7
// baseline (267.229 us; speedup 1.0000x reference)
//
#include <hip/hip_runtime.h>

#define NN 50000
#define NE 800000
#define D 128
#define NEG 0.2f

#define NEB 1024         // edge blocks (hist+scatter) in setup
#define TILE1 782        // ceil(NE / NEB)
#define NB2 196          // coarse buckets (dst>>8)
#define CAPB 32          // per-(bucket,block) cell capacity (Poisson(4) -> safe)
#define NT64 782         // ceil(NN/64) row tiles

// setup kernel block ranges: edges FIRST (longest serial tail starts earliest)
#define SB_PREP 576              // 9 matrices x 64 blocks
#define SB_CONV 6250             // NN*D/4/256
#define SB_TOTAL (NEB + SB_PREP + SB_CONV)

typedef short bf8_t __attribute__((ext_vector_type(8)));   // 8 x bf16 (16 B)
typedef float f4_t __attribute__((ext_vector_type(4)));

__device__ __forceinline__ unsigned short f2bf(float f) {
  unsigned int u = __float_as_uint(f);
  return (unsigned short)((u + 0x7FFF + ((u >> 16) & 1)) >> 16);  // RNE
}
__device__ __forceinline__ float bf2f(unsigned int b) { return __uint_as_float(b << 16); }

__device__ __forceinline__ f4_t MF(bf8_t a, bf8_t b, f4_t c) {
  return __builtin_amdgcn_mfma_f32_16x16x32_bf16(a, b, c, 0, 0, 0);
}

// LDS tile swizzle: 16B unit u, row = u>>4 (16 units per 128-col bf16 row).
// XOR row's low 3 bits into the unit index -> ds_read_b128 at the 8-beat floor.
__device__ __forceinline__ int swz_u(int u) { return u ^ ((u >> 4) & 7); }

// exclusive scan of 256 values (one per thread); wsum = 4-int LDS scratch.
// NOTE: contains one __syncthreads; caller must sync before reusing wsum.
__device__ __forceinline__ int excl_scan256(int x, int t, int* wsum) {
  const int lane = t & 63, wave = t >> 6;
  int v = x;
#pragma unroll
  for (int off = 1; off < 64; off <<= 1) {
    int y = __shfl_up(v, off, 64);
    if (lane >= off) v += y;
  }
  if (lane == 63) wsum[wave] = v;
  __syncthreads();
  int wbase = 0;
  for (int w = 0; w < wave; ++w) wbase += wsum[w];
  return wbase + v - x;
}

// ---------------- GEMM building blocks ------------------------------------------------
// wbuf holds HALF a weight matrix (64 out-cols x 128 k = 16 KB).

__device__ __forceinline__ void stage_wh(unsigned short* wbuf,
                                         const unsigned short* __restrict__ WTh, int t) {
#pragma unroll
  for (int i = 0; i < 4; ++i) {
    int u = t + i * 256;                       // 1024 units = 64 rows x 16
    *(uint4*)(wbuf + swz_u(u) * 8) = *(const uint4*)(WTh + u * 8);
  }
}

__device__ __forceinline__ void load_a16(const unsigned short* __restrict__ A,
                                         int base, int l15, int quad, bf8_t (&afr)[4]) {
  int r = base + l15;
  if (r >= NN) r = NN - 1;
  const unsigned short* p = A + (size_t)r * D + quad * 8;
#pragma unroll
  for (int kc = 0; kc < 4; ++kc) afr[kc] = *(const bf8_t*)(p + kc * 32);
}

// A-fragments from a swizzled 64x128 LDS tile
__device__ __forceinline__ void load_a16_lds(const unsigned short* buf, int wave,
                                             int l15, int quad, bf8_t (&afr)[4]) {
  const int r = wave * 16 + l15;
#pragma unroll
  for (int kc = 0; kc < 4; ++kc)
    afr[kc] = *(const bf8_t*)(buf + swz_u(r * 16 + kc * 4 + quad) * 8);
}

// one half: 4 output n-tiles (64 cols), 16 MFMAs
__device__ __forceinline__ void tile16h(const unsigned short* wbuf, const bf8_t (&afr)[4],
                                        int l15, int quad, f4_t* acc4) {
#pragma unroll
  for (int kc = 0; kc < 4; ++kc)
#pragma unroll
    for (int nt = 0; nt < 4; ++nt) {
      bf8_t b = *(const bf8_t*)(wbuf + swz_u((nt * 16 + l15) * 16 + kc * 4 + quad) * 8);
      acc4[nt] = MF(afr[kc], b, acc4[nt]);
    }
}

// acc[j] covers col = (j>>2)*64 + (j&3)*16 + l15
__device__ __forceinline__ void store_c8(unsigned short* __restrict__ C,
                                         const float* __restrict__ bias,
                                         const f4_t (&acc)[8], int base, int l15,
                                         int quad, bool lk) {
#pragma unroll
  for (int j = 0; j < 8; ++j) {
    int col = (j >> 2) * 64 + (j & 3) * 16 + l15;
    float bb = bias[col];
#pragma unroll
    for (int reg = 0; reg < 4; ++reg) {
      int row = base + quad * 4 + reg;
      if (row < NN) {
        float v = acc[j][reg] + bb;
        if (lk) v = v >= 0.f ? v : NEG * v;
        C[(size_t)row * D + col] = f2bf(v);
      }
    }
  }
}

// write leaky(acc+bias) into abuf (swizzled), rows local to tile
#define ACC_TO_ABUF(ACC, BIAS)                                        \
  {                                                                   \
    _Pragma("unroll") for (int j = 0; j < 8; ++j) {                   \
      int col = (j >> 2) * 64 + (j & 3) * 16 + l15;                   \
      float bb = (BIAS)[col];                                         \
      _Pragma("unroll") for (int reg = 0; reg < 4; ++reg) {           \
        int rl = wave * 16 + quad * 4 + reg;                          \
        float v = ACC[j][reg] + bb;                                   \
        v = v >= 0.f ? v : NEG * v;                                   \
        int s = rl * D + col;                                         \
        abuf[s ^ ((rl & 7) << 3)] = f2bf(v);                          \
      }                                                               \
    }                                                                 \
  }

// ---------------- setup: fused hist/scatter (first) + weight prep + feats convert ----
// Edge blocks scatter into private cells ebuf2[bucket][blk][CAPB] via block-local LDS
// cursors; counts to H_T[blk][bucket]; per-bucket totals accumulated into btot[].
__global__ __launch_bounds__(256) void setup(
    const float* __restrict__ Wq, const float* __restrict__ Wk,
    const float* __restrict__ Wr, const float* __restrict__ Wro,
    const float* __restrict__ feats, const int* __restrict__ src,
    const int* __restrict__ dst,
    unsigned short* __restrict__ WT, unsigned short* __restrict__ x0,
    unsigned int* __restrict__ ebuf2, int* __restrict__ H_T,
    int* __restrict__ btot) {
  __shared__ int cnt[NB2];
  const int b = blockIdx.x;
  const int t = threadIdx.x;
  if (b < NEB) {
    const int blk = b;
    if (t < NB2) cnt[t] = 0;
    __syncthreads();
    const int beg = blk * TILE1;
    int end = beg + TILE1;
    if (end > NE) end = NE;
    for (int i = beg + t; i < end; i += 256) {
      unsigned int d = (unsigned int)dst[i];
      unsigned int s = (unsigned int)src[i];
      int bkt = (int)(d >> 8);
      int pos = atomicAdd(&cnt[bkt], 1);
      if (pos < CAPB)
        ebuf2[((size_t)bkt * NEB + blk) * CAPB + pos] = s | (d << 16);
    }
    __syncthreads();
    if (t < NB2) {
      H_T[blk * NB2 + t] = cnt[t];
      if (cnt[t]) atomicAdd(&btot[t], cnt[t]);
    }
  } else if (b < NEB + SB_PREP) {
    const int pb = b - NEB;
    const int m = pb >> 6, xb = pb & 63;
    const float* sp;
    if (m < 2) sp = Wq + m * D * D;
    else if (m < 4) sp = Wk + (m - 2) * D * D;
    else if (m < 6) sp = Wr + (m - 4) * D * D;
    else sp = Wro + (m - 6) * D * D;
    const int n = xb * 2 + (t >> 7);
    const int k = t & 127;
    WT[(size_t)m * D * D + n * D + k] = f2bf(sp[k * D + n]);
  } else {
    int i = ((b - NEB - SB_PREP) * 256 + t) * 4;
    float4 v = *(const float4*)(feats + i);
    ushort4 o = {f2bf(v.x), f2bf(v.y), f2bf(v.z), f2bf(v.w)};
    *(ushort4*)(x0 + i) = o;
  }
}

// ---------------- merged: per-bucket counting sort (196 blocks) + layer-0 Q/K GEMMs --
// Sort block b: bucket bases from btot scan; thread t drains cells {t+256c}.
// GEMM: Q and K in PARALLEL blocks (5 barrier-phases each, half the critical path).
// grid = 196 + 1564 = 1760 <= 2048 resident (16 KB LDS, 8 blk/CU wave cap): one round.
__global__ __launch_bounds__(256) void sort_qk0(
    const int* __restrict__ H_T, const int* __restrict__ btot,
    const unsigned int* __restrict__ ebuf2,
    int* __restrict__ ssrc, int* __restrict__ rowptr, int* __restrict__ deg,
    const unsigned short* __restrict__ x0,
    const unsigned short* __restrict__ WTq, const float* __restrict__ bq_,
    const unsigned short* __restrict__ WTk, const float* __restrict__ bk_,
    unsigned short* __restrict__ hq, unsigned short* __restrict__ hk) {
  __shared__ __align__(16) unsigned char smraw[16384];  // GEMM 16KB / sort ~3.1KB
  const int t = threadIdx.x;
  const int gx = blockIdx.x;
  if (gx < NB2) {
    int* cnt = (int*)smraw;          // 256: per-node counts
    int* fill = cnt + 256;           // 256: per-node cursors
    int* sc = fill + 256;            // 256: bucket bases
    int* wsum = sc + 256;            // 4
    const int b = gx;
    // bucket bases from btot (196 values) -> exclusive scan
    int tot = (t < NB2) ? btot[t] : 0;
    int bbase = excl_scan256(tot, t, wsum);
    sc[t] = bbase;
    __syncthreads();
    const int beg = sc[b];
    // per-cell counts: thread t drains cells blk = t + 256c for bucket b
    int cj[4];
    const unsigned int* cell[4];
#pragma unroll
    for (int c = 0; c < 4; ++c) {
      int blk = t + 256 * c;
      int n = H_T[blk * NB2 + b];
      cj[c] = n > CAPB ? CAPB : n;
      cell[c] = ebuf2 + ((size_t)b * NEB + blk) * CAPB;
    }
    cnt[t] = 0;
    __syncthreads();
#pragma unroll
    for (int c = 0; c < 4; ++c)
      for (int i = 0; i < cj[c]; ++i)
        atomicAdd(&cnt[(cell[c][i] >> 16) & 255], 1);
    __syncthreads();
    const int x = cnt[t];
    const int excl = excl_scan256(x, t, wsum);
    fill[t] = excl;
    const int node = (b << 8) + t;
    if (node < NN) {
      rowptr[node] = beg + excl;
      deg[node] = x;
    }
    if (b == 0 && t == 0) rowptr[NN] = NE;
    __syncthreads();
#pragma unroll
    for (int c = 0; c < 4; ++c)
      for (int i = 0; i < cj[c]; ++i) {
        unsigned int p = cell[c][i];
        int pos = atomicAdd(&fill[(p >> 16) & 255], 1);
        ssrc[beg + pos] = (int)(p & 0xFFFFu);
      }
  } else {
    unsigned short* wbuf = (unsigned short*)smraw;
    const int g = gx - NB2;
    const int sel = g & 1, tile = g >> 1;
    const int wave = t >> 6, lane = t & 63;
    const int l15 = lane & 15, quad = lane >> 4;
    const int base = tile * 64 + wave * 16;
    const unsigned short* WT_ = sel ? WTk : WTq;
    bf8_t afr[4];
    load_a16(x0, base, l15, quad, afr);
    stage_wh(wbuf, WT_, t);
    __syncthreads();
    f4_t acc[8] = {};
    tile16h(wbuf, afr, l15, quad, acc);
    __syncthreads();
    stage_wh(wbuf, WT_ + 64 * D, t);
    __syncthreads();
    tile16h(wbuf, afr, l15, quad, acc + 4);
    store_c8(sel ? hk : hq, sel ? bk_ : bq_, acc, base, l15, quad, false);
  }
}

// ---------------- aggregation: high-TLP gather, one node per wave --------------------
#define PROC(kb)                                                     \
  {                                                                  \
    float m;                                                         \
    m = q[0] + bf2f(kb.x & 0xFFFFu); a[0] += m >= 0.f ? m : NEG * m; \
    m = q[1] + bf2f(kb.x >> 16);     a[1] += m >= 0.f ? m : NEG * m; \
    m = q[2] + bf2f(kb.y & 0xFFFFu); a[2] += m >= 0.f ? m : NEG * m; \
    m = q[3] + bf2f(kb.y >> 16);     a[3] += m >= 0.f ? m : NEG * m; \
    m = q[4] + bf2f(kb.z & 0xFFFFu); a[4] += m >= 0.f ? m : NEG * m; \
    m = q[5] + bf2f(kb.z >> 16);     a[5] += m >= 0.f ? m : NEG * m; \
    m = q[6] + bf2f(kb.w & 0xFFFFu); a[6] += m >= 0.f ? m : NEG * m; \
    m = q[7] + bf2f(kb.w >> 16);     a[7] += m >= 0.f ? m : NEG * m; \
  }

__global__ __launch_bounds__(256) void aggregate(
    const int* __restrict__ rowptr, const int* __restrict__ ssrc,
    const int* __restrict__ deg,
    const unsigned short* __restrict__ hq, const unsigned short* __restrict__ hk,
    unsigned short* __restrict__ ag) {
  const int wave = threadIdx.x >> 6, lane = threadIdx.x & 63;
  const int v = blockIdx.x * 4 + wave;
  if (v >= NN) return;
  const int sub = lane & 15, grp = lane >> 4;
  const int beg = rowptr[v], end = rowptr[v + 1];

  uint4 qb = *(const uint4*)(hq + (size_t)v * D + sub * 8);
  float q[8];
  q[0] = bf2f(qb.x & 0xFFFFu); q[1] = bf2f(qb.x >> 16);
  q[2] = bf2f(qb.y & 0xFFFFu); q[3] = bf2f(qb.y >> 16);
  q[4] = bf2f(qb.z & 0xFFFFu); q[5] = bf2f(qb.z >> 16);
  q[6] = bf2f(qb.w & 0xFFFFu); q[7] = bf2f(qb.w >> 16);

  float a[8] = {0.f, 0.f, 0.f, 0.f, 0.f, 0.f, 0.f, 0.f};
  int e = beg + grp;
  for (; e + 12 < end; e += 16) {  // 4 edge streams -> 16 x 16B in flight per wave
    int s0 = ssrc[e];
    int s1 = ssrc[e + 4];
    int s2 = ssrc[e + 8];
    int s3 = ssrc[e + 12];
    uint4 k0 = *(const uint4*)(hk + (size_t)s0 * D + sub * 8);
    uint4 k1 = *(const uint4*)(hk + (size_t)s1 * D + sub * 8);
    uint4 k2 = *(const uint4*)(hk + (size_t)s2 * D + sub * 8);
    uint4 k3 = *(const uint4*)(hk + (size_t)s3 * D + sub * 8);
    PROC(k0);
    PROC(k1);
    PROC(k2);
    PROC(k3);
  }
  for (; e + 4 < end; e += 8) {    // pair tail
    int s0 = ssrc[e];
    int s1 = ssrc[e + 4];
    uint4 k0 = *(const uint4*)(hk + (size_t)s0 * D + sub * 8);
    uint4 k1 = *(const uint4*)(hk + (size_t)s1 * D + sub * 8);
    PROC(k0);
    PROC(k1);
  }
  if (e < end) {
    int s0 = ssrc[e];
    uint4 k0 = *(const uint4*)(hk + (size_t)s0 * D + sub * 8);
    PROC(k0);
  }
#pragma unroll
  for (int j = 0; j < 8; ++j) {
    a[j] += __shfl_xor(a[j], 16, 64);
    a[j] += __shfl_xor(a[j], 32, 64);
  }
  if (grp == 0) {
    float inv = 1.f / fmaxf((float)deg[v], 1.f);
    uint4 o;
    o.x = (unsigned int)f2bf(a[0] * inv) | ((unsigned int)f2bf(a[1] * inv) << 16);
    o.y = (unsigned int)f2bf(a[2] * inv) | ((unsigned int)f2bf(a[3] * inv) << 16);
    o.z = (unsigned int)f2bf(a[4] * inv) | ((unsigned int)f2bf(a[5] * inv) << 16);
    o.w = (unsigned int)f2bf(a[6] * inv) | ((unsigned int)f2bf(a[7] * inv) << 16);
    *(uint4*)(ag + (size_t)v * D + sub * 8) = o;
  }
}

// ---------------- fused: h1 = leaky(ag@Wr0 + br0); hq = h1@Wq1; hk = h1@Wk1 ----------
// 32 KB LDS -> 5 blocks/CU -> 782 blocks in a single residency round.
__global__ __launch_bounds__(256) void wr_qk1(
    const unsigned short* __restrict__ ag,
    const unsigned short* __restrict__ WTr, const float* __restrict__ brr,
    unsigned short* __restrict__ h1,
    const unsigned short* __restrict__ WTq, const float* __restrict__ bq1,
    unsigned short* __restrict__ hq,
    const unsigned short* __restrict__ WTk, const float* __restrict__ bk1,
    unsigned short* __restrict__ hk) {
  __shared__ unsigned short wbuf[64 * D];  // 16 KB (half weight)
  __shared__ unsigned short abuf[64 * D];  // 16 KB (swizzled h1 tile)
  const int t = threadIdx.x, wave = t >> 6, lane = t & 63;
  const int l15 = lane & 15, quad = lane >> 4;
  const int tb = blockIdx.x * 64;
  const int base = tb + wave * 16;

  // phase 0: acc = ag @ Wr0 (two halves)
  bf8_t afr[4];
  load_a16(ag, base, l15, quad, afr);
  stage_wh(wbuf, WTr, t);
  __syncthreads();
  f4_t acc[8] = {};
  tile16h(wbuf, afr, l15, quad, acc);
  __syncthreads();
  stage_wh(wbuf, WTr + 64 * D, t);
  __syncthreads();
  tile16h(wbuf, afr, l15, quad, acc + 4);

  ACC_TO_ABUF(acc, brr);           // h1 tile -> abuf (own elements, no hazard)
  __syncthreads();

  bf8_t hfr[4];
  load_a16_lds(abuf, wave, l15, quad, hfr);
  // coalesced h1 global write straight from LDS
#pragma unroll
  for (int i = 0; i < 4; ++i) {
    int u = t + i * 256;
    int row = tb + (u >> 4);
    if (row < NN)
      *(uint4*)(h1 + (size_t)tb * D + u * 8) = *(const uint4*)(abuf + swz_u(u) * 8);
  }

  // hq = h1 @ Wq1 + bq1
  stage_wh(wbuf, WTq, t);
  __syncthreads();
  f4_t aq[8] = {};
  tile16h(wbuf, hfr, l15, quad, aq);
  __syncthreads();
  stage_wh(wbuf, WTq + 64 * D, t);
  __syncthreads();
  tile16h(wbuf, hfr, l15, quad, aq + 4);
  store_c8(hq, bq1, aq, base, l15, quad, false);
  __syncthreads();

  // hk = h1 @ Wk1 + bk1
  stage_wh(wbuf, WTk, t);
  __syncthreads();
  f4_t ak[8] = {};
  tile16h(wbuf, hfr, l15, quad, ak);
  __syncthreads();
  stage_wh(wbuf, WTk + 64 * D, t);
  __syncthreads();
  tile16h(wbuf, hfr, l15, quad, ak + 4);
  store_c8(hk, bk1, ak, base, l15, quad, false);
}

// ---------------- fused: h2 = leaky(ag@Wr1 + br1) (LDS only) + JK readout ------------
__global__ __launch_bounds__(256) void wr_ro(
    const unsigned short* __restrict__ ag,
    const unsigned short* __restrict__ WTr, const float* __restrict__ brr,
    const unsigned short* __restrict__ x0,
    const unsigned short* __restrict__ h1,
    const unsigned short* __restrict__ WTro, const float* __restrict__ bro_,
    float* __restrict__ out) {
  __shared__ unsigned short wbuf[64 * D];  // 16 KB
  __shared__ unsigned short abuf[64 * D];  // 16 KB
  const int t = threadIdx.x, wave = t >> 6, lane = t & 63;
  const int l15 = lane & 15, quad = lane >> 4;
  const int tb = blockIdx.x * 64;
  const int base = tb + wave * 16;
  const size_t WM = (size_t)D * D;

  // phase 0: acch = ag @ Wr1 (two halves)
  bf8_t afr[4];
  load_a16(ag, base, l15, quad, afr);
  stage_wh(wbuf, WTr, t);
  __syncthreads();
  f4_t acch[8] = {};
  tile16h(wbuf, afr, l15, quad, acch);
  __syncthreads();
  stage_wh(wbuf, WTr + 64 * D, t);
  __syncthreads();
  tile16h(wbuf, afr, l15, quad, acch + 4);

  ACC_TO_ABUF(acch, brr);          // h2 tile -> abuf (never touches global)
  __syncthreads();

  bf8_t hfr[4];
  load_a16_lds(abuf, wave, l15, quad, hfr);
  f4_t acc[8] = {};

  // acc += h2 @ Wro2
  stage_wh(wbuf, WTro + 2 * WM, t);
  __syncthreads();
  tile16h(wbuf, hfr, l15, quad, acc);
  __syncthreads();
  stage_wh(wbuf, WTro + 2 * WM + 64 * D, t);
  __syncthreads();
  tile16h(wbuf, hfr, l15, quad, acc + 4);
  __syncthreads();

  // acc += x0 @ Wro0
  load_a16(x0, base, l15, quad, afr);
  stage_wh(wbuf, WTro, t);
  __syncthreads();
  tile16h(wbuf, afr, l15, quad, acc);
  __syncthreads();
  stage_wh(wbuf, WTro + 64 * D, t);
  __syncthreads();
  tile16h(wbuf, afr, l15, quad, acc + 4);
  __syncthreads();

  // acc += h1 @ Wro1
  load_a16(h1, base, l15, quad, afr);
  stage_wh(wbuf, WTro + WM, t);
  __syncthreads();
  tile16h(wbuf, afr, l15, quad, acc);
  __syncthreads();
  stage_wh(wbuf, WTro + WM + 64 * D, t);
  __syncthreads();
  tile16h(wbuf, afr, l15, quad, acc + 4);

#pragma unroll
  for (int j = 0; j < 8; ++j) {
    int col = (j >> 2) * 64 + (j & 3) * 16 + l15;
    float bsum = bro_[col] + bro_[D + col] + bro_[2 * D + col];
#pragma unroll
    for (int reg = 0; reg < 4; ++reg) {
      int row = base + quad * 4 + reg;
      if (row < NN) out[(size_t)row * D + col] = acc[j][reg] + bsum;
    }
  }
}

// ---------------- launch ----------------
extern "C" void kernel_launch(void* const* d_in, const int* in_sizes, int n_in,
                              void* d_out, int out_size, void* d_ws, size_t ws_size,
                              hipStream_t stream) {
  const float* feats = (const float*)d_in[0];
  const float* Wq = (const float*)d_in[1];
  const float* bq = (const float*)d_in[2];
  const float* Wk = (const float*)d_in[3];
  const float* bk = (const float*)d_in[4];
  const float* Wr = (const float*)d_in[5];
  const float* br = (const float*)d_in[6];
  const float* Wro = (const float*)d_in[7];
  const float* bro = (const float*)d_in[8];
  const int* src = (const int*)d_in[9];
  const int* dst = (const int*)d_in[10];
  float* out = (float*)d_out;

  size_t off = 0;
  char* base = (char*)d_ws;
  auto alloc = [&](size_t bytes) -> void* {
    void* p = base + off;
    off += (bytes + 255) & ~(size_t)255;
    return p;
  };
  int* H_T = (int*)alloc((size_t)NEB * NB2 * 4);
  int* btot = (int*)alloc((size_t)NB2 * 4);
  unsigned int* ebuf2 = (unsigned int*)alloc((size_t)NB2 * NEB * CAPB * 4);
  int* ssrc = (int*)alloc((size_t)NE * 4);
  int* rowptr = (int*)alloc((size_t)(NN + 1) * 4);
  int* deg = (int*)alloc((size_t)NN * 4);
  unsigned short* WT = (unsigned short*)alloc((size_t)9 * D * D * 2);
  unsigned short* x0 = (unsigned short*)alloc((size_t)NN * D * 2);
  unsigned short* hq = (unsigned short*)alloc((size_t)NN * D * 2);
  unsigned short* hk = (unsigned short*)alloc((size_t)NN * D * 2);
  unsigned short* ag = (unsigned short*)alloc((size_t)NN * D * 2);
  unsigned short* h1 = (unsigned short*)alloc((size_t)NN * D * 2);

  const size_t WM = (size_t)D * D;
  const int ab = (NN + 3) / 4;

  // 0: zero bucket totals (tiny)
  hipMemsetAsync(btot, 0, (size_t)NB2 * 4, stream);
  // 1: fused hist/scatter (edge blocks first) + weights + feats convert
  setup<<<SB_TOTAL, 256, 0, stream>>>(Wq, Wk, Wr, Wro, feats, src, dst,
                                      WT, x0, ebuf2, H_T, btot);
  // 2: per-bucket counting sort (196, cell-drain) + layer-0 Q/K GEMMs (1564 parallel)
  sort_qk0<<<NB2 + 2 * NT64, 256, 0, stream>>>(H_T, btot, ebuf2, ssrc, rowptr, deg,
                                               x0, WT + 0 * WM, bq, WT + 2 * WM, bk,
                                               hq, hk);
  // 3: layer-0 aggregate (high-TLP: one node per wave)
  aggregate<<<ab, 256, 0, stream>>>(rowptr, ssrc, deg, hq, hk, ag);
  // 4: fused h1 = leaky(ag@Wr0), hq/hk = h1@Wq1/Wk1 (single round)
  wr_qk1<<<NT64, 256, 0, stream>>>(ag, WT + 4 * WM, br, h1,
                                   WT + 1 * WM, bq + D, hq,
                                   WT + 3 * WM, bk + D, hk);
  // 5: layer-1 aggregate
  aggregate<<<ab, 256, 0, stream>>>(rowptr, ssrc, deg, hq, hk, ag);
  // 6: fused h2 = leaky(ag@Wr1) (LDS-only) + JK readout (single round)
  wr_ro<<<NT64, 256, 0, stream>>>(ag, WT + 5 * WM, br + D, x0, h1,
                                  WT + 6 * WM, bro, out);
}

// Round 8
// 267.100 us; speedup vs baseline: 1.0005x; 1.0005x over previous
//
#include <hip/hip_runtime.h>

#define NN 50000
#define NE 800000
#define D 128
#define NEG 0.2f

#define NEB 1024         // edge blocks (hist+scatter) in setup
#define TILE1 782        // ceil(NE / NEB)
#define NB2 196          // coarse buckets (dst>>8)
#define CAPB 32          // per-(bucket,block) cell capacity (Poisson(4) -> safe)
#define NT64 782         // ceil(NN/64) row tiles

// setup kernel block ranges: edges FIRST (longest serial tail starts earliest)
#define SB_PREP 576              // 9 matrices x 64 blocks
#define SB_CONV 6250             // NN*D/4/256
#define SB_TOTAL (NEB + SB_PREP + SB_CONV)

typedef short bf8_t __attribute__((ext_vector_type(8)));   // 8 x bf16 (16 B)
typedef float f4_t __attribute__((ext_vector_type(4)));

__device__ __forceinline__ unsigned short f2bf(float f) {
  unsigned int u = __float_as_uint(f);
  return (unsigned short)((u + 0x7FFF + ((u >> 16) & 1)) >> 16);  // RNE
}
__device__ __forceinline__ float bf2f(unsigned int b) { return __uint_as_float(b << 16); }

__device__ __forceinline__ f4_t MF(bf8_t a, bf8_t b, f4_t c) {
  return __builtin_amdgcn_mfma_f32_16x16x32_bf16(a, b, c, 0, 0, 0);
}

// LDS tile swizzle: 16B unit u, row = u>>4 (16 units per 128-col bf16 row).
// XOR row's low 3 bits into the unit index -> ds_read_b128 at the 8-beat floor.
__device__ __forceinline__ int swz_u(int u) { return u ^ ((u >> 4) & 7); }

// exclusive scan of 256 values (one per thread); wsum = 4-int LDS scratch.
// NOTE: contains one __syncthreads; caller must sync before reusing wsum.
__device__ __forceinline__ int excl_scan256(int x, int t, int* wsum) {
  const int lane = t & 63, wave = t >> 6;
  int v = x;
#pragma unroll
  for (int off = 1; off < 64; off <<= 1) {
    int y = __shfl_up(v, off, 64);
    if (lane >= off) v += y;
  }
  if (lane == 63) wsum[wave] = v;
  __syncthreads();
  int wbase = 0;
  for (int w = 0; w < wave; ++w) wbase += wsum[w];
  return wbase + v - x;
}

// ---------------- GEMM building blocks ------------------------------------------------
// wbuf holds HALF a weight matrix (64 out-cols x 128 k = 16 KB).

__device__ __forceinline__ void stage_wh(unsigned short* wbuf,
                                         const unsigned short* __restrict__ WTh, int t) {
#pragma unroll
  for (int i = 0; i < 4; ++i) {
    int u = t + i * 256;                       // 1024 units = 64 rows x 16
    *(uint4*)(wbuf + swz_u(u) * 8) = *(const uint4*)(WTh + u * 8);
  }
}

__device__ __forceinline__ void load_a16(const unsigned short* __restrict__ A,
                                         int base, int l15, int quad, bf8_t (&afr)[4]) {
  int r = base + l15;
  if (r >= NN) r = NN - 1;
  const unsigned short* p = A + (size_t)r * D + quad * 8;
#pragma unroll
  for (int kc = 0; kc < 4; ++kc) afr[kc] = *(const bf8_t*)(p + kc * 32);
}

// A-fragments from a swizzled 64x128 LDS tile
__device__ __forceinline__ void load_a16_lds(const unsigned short* buf, int wave,
                                             int l15, int quad, bf8_t (&afr)[4]) {
  const int r = wave * 16 + l15;
#pragma unroll
  for (int kc = 0; kc < 4; ++kc)
    afr[kc] = *(const bf8_t*)(buf + swz_u(r * 16 + kc * 4 + quad) * 8);
}

// one half: 4 output n-tiles (64 cols), 16 MFMAs
__device__ __forceinline__ void tile16h(const unsigned short* wbuf, const bf8_t (&afr)[4],
                                        int l15, int quad, f4_t* acc4) {
#pragma unroll
  for (int kc = 0; kc < 4; ++kc)
#pragma unroll
    for (int nt = 0; nt < 4; ++nt) {
      bf8_t b = *(const bf8_t*)(wbuf + swz_u((nt * 16 + l15) * 16 + kc * 4 + quad) * 8);
      acc4[nt] = MF(afr[kc], b, acc4[nt]);
    }
}

// acc[j] covers col = (j>>2)*64 + (j&3)*16 + l15
__device__ __forceinline__ void store_c8(unsigned short* __restrict__ C,
                                         const float* __restrict__ bias,
                                         const f4_t (&acc)[8], int base, int l15,
                                         int quad, bool lk) {
#pragma unroll
  for (int j = 0; j < 8; ++j) {
    int col = (j >> 2) * 64 + (j & 3) * 16 + l15;
    float bb = bias[col];
#pragma unroll
    for (int reg = 0; reg < 4; ++reg) {
      int row = base + quad * 4 + reg;
      if (row < NN) {
        float v = acc[j][reg] + bb;
        if (lk) v = v >= 0.f ? v : NEG * v;
        C[(size_t)row * D + col] = f2bf(v);
      }
    }
  }
}

// write leaky(acc+bias) into abuf (swizzled), rows local to tile
#define ACC_TO_ABUF(ACC, BIAS)                                        \
  {                                                                   \
    _Pragma("unroll") for (int j = 0; j < 8; ++j) {                   \
      int col = (j >> 2) * 64 + (j & 3) * 16 + l15;                   \
      float bb = (BIAS)[col];                                         \
      _Pragma("unroll") for (int reg = 0; reg < 4; ++reg) {           \
        int rl = wave * 16 + quad * 4 + reg;                          \
        float v = ACC[j][reg] + bb;                                   \
        v = v >= 0.f ? v : NEG * v;                                   \
        int s = rl * D + col;                                         \
        abuf[s ^ ((rl & 7) << 3)] = f2bf(v);                          \
      }                                                               \
    }                                                                 \
  }

// ---------------- setup: fused hist/scatter (first) + weight prep + feats convert ----
// Edge blocks scatter into private cells ebuf2[bucket][blk][CAPB] via block-local LDS
// cursors; counts to H_T[blk][bucket]; per-bucket totals accumulated into btot[].
__global__ __launch_bounds__(256) void setup(
    const float* __restrict__ Wq, const float* __restrict__ Wk,
    const float* __restrict__ Wr, const float* __restrict__ Wro,
    const float* __restrict__ feats, const int* __restrict__ src,
    const int* __restrict__ dst,
    unsigned short* __restrict__ WT, unsigned short* __restrict__ x0,
    unsigned int* __restrict__ ebuf2, int* __restrict__ H_T,
    int* __restrict__ btot) {
  __shared__ int cnt[NB2];
  const int b = blockIdx.x;
  const int t = threadIdx.x;
  if (b < NEB) {
    const int blk = b;
    if (t < NB2) cnt[t] = 0;
    __syncthreads();
    const int beg = blk * TILE1;
    int end = beg + TILE1;
    if (end > NE) end = NE;
    for (int i = beg + t; i < end; i += 256) {
      unsigned int d = (unsigned int)dst[i];
      unsigned int s = (unsigned int)src[i];
      int bkt = (int)(d >> 8);
      int pos = atomicAdd(&cnt[bkt], 1);
      if (pos < CAPB)
        ebuf2[((size_t)bkt * NEB + blk) * CAPB + pos] = s | (d << 16);
    }
    __syncthreads();
    if (t < NB2) {
      H_T[blk * NB2 + t] = cnt[t];
      if (cnt[t]) atomicAdd(&btot[t], cnt[t]);
    }
  } else if (b < NEB + SB_PREP) {
    const int pb = b - NEB;
    const int m = pb >> 6, xb = pb & 63;
    const float* sp;
    if (m < 2) sp = Wq + m * D * D;
    else if (m < 4) sp = Wk + (m - 2) * D * D;
    else if (m < 6) sp = Wr + (m - 4) * D * D;
    else sp = Wro + (m - 6) * D * D;
    const int n = xb * 2 + (t >> 7);
    const int k = t & 127;
    WT[(size_t)m * D * D + n * D + k] = f2bf(sp[k * D + n]);
  } else {
    int i = ((b - NEB - SB_PREP) * 256 + t) * 4;
    float4 v = *(const float4*)(feats + i);
    ushort4 o = {f2bf(v.x), f2bf(v.y), f2bf(v.z), f2bf(v.w)};
    *(ushort4*)(x0 + i) = o;
  }
}

// ---------------- merged: per-bucket counting sort (196 blocks) + layer-0 Q&K GEMM ---
// Sort block b: bucket bases from btot scan; thread t drains cells {t+256c}.
// GEMM blocks do BOTH Wq and Wk for their 64-row tile (x0 A-fragments loaded once).
// grid = 196 + 782 = 978 <= resident capacity (16 KB LDS): single round.
__global__ __launch_bounds__(256) void sort_qk0(
    const int* __restrict__ H_T, const int* __restrict__ btot,
    const unsigned int* __restrict__ ebuf2,
    int* __restrict__ ssrc, int* __restrict__ rowptr, int* __restrict__ deg,
    const unsigned short* __restrict__ x0,
    const unsigned short* __restrict__ WTq, const float* __restrict__ bq_,
    const unsigned short* __restrict__ WTk, const float* __restrict__ bk_,
    unsigned short* __restrict__ hq, unsigned short* __restrict__ hk) {
  __shared__ __align__(16) unsigned char smraw[16384];  // GEMM 16KB / sort ~3.1KB
  const int t = threadIdx.x;
  const int gx = blockIdx.x;
  if (gx < NB2) {
    int* cnt = (int*)smraw;          // 256: per-node counts
    int* fill = cnt + 256;           // 256: per-node cursors
    int* sc = fill + 256;            // 256: bucket bases
    int* wsum = sc + 256;            // 4
    const int b = gx;
    // bucket bases from btot (196 values) -> exclusive scan
    int tot = (t < NB2) ? btot[t] : 0;
    int bbase = excl_scan256(tot, t, wsum);
    sc[t] = bbase;
    __syncthreads();
    const int beg = sc[b];
    // per-cell counts: thread t drains cells blk = t + 256c for bucket b
    int cj[4];
    const unsigned int* cell[4];
#pragma unroll
    for (int c = 0; c < 4; ++c) {
      int blk = t + 256 * c;
      int n = H_T[blk * NB2 + b];
      cj[c] = n > CAPB ? CAPB : n;
      cell[c] = ebuf2 + ((size_t)b * NEB + blk) * CAPB;
    }
    cnt[t] = 0;
    __syncthreads();
#pragma unroll
    for (int c = 0; c < 4; ++c)
      for (int i = 0; i < cj[c]; ++i)
        atomicAdd(&cnt[(cell[c][i] >> 16) & 255], 1);
    __syncthreads();
    const int x = cnt[t];
    const int excl = excl_scan256(x, t, wsum);
    fill[t] = excl;
    const int node = (b << 8) + t;
    if (node < NN) {
      rowptr[node] = beg + excl;
      deg[node] = x;
    }
    if (b == 0 && t == 0) rowptr[NN] = NE;
    __syncthreads();
#pragma unroll
    for (int c = 0; c < 4; ++c)
      for (int i = 0; i < cj[c]; ++i) {
        unsigned int p = cell[c][i];
        int pos = atomicAdd(&fill[(p >> 16) & 255], 1);
        ssrc[beg + pos] = (int)(p & 0xFFFFu);
      }
  } else {
    unsigned short* wbuf = (unsigned short*)smraw;
    const int tile = gx - NB2;
    const int wave = t >> 6, lane = t & 63;
    const int l15 = lane & 15, quad = lane >> 4;
    const int base = tile * 64 + wave * 16;
    bf8_t afr[4];
    load_a16(x0, base, l15, quad, afr);
    // Q
    stage_wh(wbuf, WTq, t);
    __syncthreads();
    f4_t aq[8] = {};
    tile16h(wbuf, afr, l15, quad, aq);
    __syncthreads();
    stage_wh(wbuf, WTq + 64 * D, t);
    __syncthreads();
    tile16h(wbuf, afr, l15, quad, aq + 4);
    store_c8(hq, bq_, aq, base, l15, quad, false);
    __syncthreads();
    // K
    stage_wh(wbuf, WTk, t);
    __syncthreads();
    f4_t ak[8] = {};
    tile16h(wbuf, afr, l15, quad, ak);
    __syncthreads();
    stage_wh(wbuf, WTk + 64 * D, t);
    __syncthreads();
    tile16h(wbuf, afr, l15, quad, ak + 4);
    store_c8(hk, bk_, ak, base, l15, quad, false);
  }
}

// ---------------- aggregation: high-TLP gather, one node per wave --------------------
#define PROC(kb)                                                     \
  {                                                                  \
    float m;                                                         \
    m = q[0] + bf2f(kb.x & 0xFFFFu); a[0] += m >= 0.f ? m : NEG * m; \
    m = q[1] + bf2f(kb.x >> 16);     a[1] += m >= 0.f ? m : NEG * m; \
    m = q[2] + bf2f(kb.y & 0xFFFFu); a[2] += m >= 0.f ? m : NEG * m; \
    m = q[3] + bf2f(kb.y >> 16);     a[3] += m >= 0.f ? m : NEG * m; \
    m = q[4] + bf2f(kb.z & 0xFFFFu); a[4] += m >= 0.f ? m : NEG * m; \
    m = q[5] + bf2f(kb.z >> 16);     a[5] += m >= 0.f ? m : NEG * m; \
    m = q[6] + bf2f(kb.w & 0xFFFFu); a[6] += m >= 0.f ? m : NEG * m; \
    m = q[7] + bf2f(kb.w >> 16);     a[7] += m >= 0.f ? m : NEG * m; \
  }

__global__ __launch_bounds__(256) void aggregate(
    const int* __restrict__ rowptr, const int* __restrict__ ssrc,
    const int* __restrict__ deg,
    const unsigned short* __restrict__ hq, const unsigned short* __restrict__ hk,
    unsigned short* __restrict__ ag) {
  const int wave = threadIdx.x >> 6, lane = threadIdx.x & 63;
  const int v = blockIdx.x * 4 + wave;
  if (v >= NN) return;
  const int sub = lane & 15, grp = lane >> 4;
  const int beg = rowptr[v], end = rowptr[v + 1];

  uint4 qb = *(const uint4*)(hq + (size_t)v * D + sub * 8);
  float q[8];
  q[0] = bf2f(qb.x & 0xFFFFu); q[1] = bf2f(qb.x >> 16);
  q[2] = bf2f(qb.y & 0xFFFFu); q[3] = bf2f(qb.y >> 16);
  q[4] = bf2f(qb.z & 0xFFFFu); q[5] = bf2f(qb.z >> 16);
  q[6] = bf2f(qb.w & 0xFFFFu); q[7] = bf2f(qb.w >> 16);

  float a[8] = {0.f, 0.f, 0.f, 0.f, 0.f, 0.f, 0.f, 0.f};
  int e = beg + grp;
  for (; e + 12 < end; e += 16) {  // 4 edge streams -> 16 x 16B in flight per wave
    int s0 = ssrc[e];
    int s1 = ssrc[e + 4];
    int s2 = ssrc[e + 8];
    int s3 = ssrc[e + 12];
    uint4 k0 = *(const uint4*)(hk + (size_t)s0 * D + sub * 8);
    uint4 k1 = *(const uint4*)(hk + (size_t)s1 * D + sub * 8);
    uint4 k2 = *(const uint4*)(hk + (size_t)s2 * D + sub * 8);
    uint4 k3 = *(const uint4*)(hk + (size_t)s3 * D + sub * 8);
    PROC(k0);
    PROC(k1);
    PROC(k2);
    PROC(k3);
  }
  for (; e + 4 < end; e += 8) {    // pair tail
    int s0 = ssrc[e];
    int s1 = ssrc[e + 4];
    uint4 k0 = *(const uint4*)(hk + (size_t)s0 * D + sub * 8);
    uint4 k1 = *(const uint4*)(hk + (size_t)s1 * D + sub * 8);
    PROC(k0);
    PROC(k1);
  }
  if (e < end) {
    int s0 = ssrc[e];
    uint4 k0 = *(const uint4*)(hk + (size_t)s0 * D + sub * 8);
    PROC(k0);
  }
#pragma unroll
  for (int j = 0; j < 8; ++j) {
    a[j] += __shfl_xor(a[j], 16, 64);
    a[j] += __shfl_xor(a[j], 32, 64);
  }
  if (grp == 0) {
    float inv = 1.f / fmaxf((float)deg[v], 1.f);
    uint4 o;
    o.x = (unsigned int)f2bf(a[0] * inv) | ((unsigned int)f2bf(a[1] * inv) << 16);
    o.y = (unsigned int)f2bf(a[2] * inv) | ((unsigned int)f2bf(a[3] * inv) << 16);
    o.z = (unsigned int)f2bf(a[4] * inv) | ((unsigned int)f2bf(a[5] * inv) << 16);
    o.w = (unsigned int)f2bf(a[6] * inv) | ((unsigned int)f2bf(a[7] * inv) << 16);
    *(uint4*)(ag + (size_t)v * D + sub * 8) = o;
  }
}

// ---------------- fused: h1 = leaky(ag@Wr0 + br0); hq = h1@Wq1; hk = h1@Wk1 ----------
// 32 KB LDS -> 5 blocks/CU -> 782 blocks in a single residency round.
__global__ __launch_bounds__(256) void wr_qk1(
    const unsigned short* __restrict__ ag,
    const unsigned short* __restrict__ WTr, const float* __restrict__ brr,
    unsigned short* __restrict__ h1,
    const unsigned short* __restrict__ WTq, const float* __restrict__ bq1,
    unsigned short* __restrict__ hq,
    const unsigned short* __restrict__ WTk, const float* __restrict__ bk1,
    unsigned short* __restrict__ hk) {
  __shared__ unsigned short wbuf[64 * D];  // 16 KB (half weight)
  __shared__ unsigned short abuf[64 * D];  // 16 KB (swizzled h1 tile)
  const int t = threadIdx.x, wave = t >> 6, lane = t & 63;
  const int l15 = lane & 15, quad = lane >> 4;
  const int tb = blockIdx.x * 64;
  const int base = tb + wave * 16;

  // phase 0: acc = ag @ Wr0 (two halves)
  bf8_t afr[4];
  load_a16(ag, base, l15, quad, afr);
  stage_wh(wbuf, WTr, t);
  __syncthreads();
  f4_t acc[8] = {};
  tile16h(wbuf, afr, l15, quad, acc);
  __syncthreads();
  stage_wh(wbuf, WTr + 64 * D, t);
  __syncthreads();
  tile16h(wbuf, afr, l15, quad, acc + 4);

  ACC_TO_ABUF(acc, brr);           // h1 tile -> abuf (own elements, no hazard)
  __syncthreads();

  bf8_t hfr[4];
  load_a16_lds(abuf, wave, l15, quad, hfr);
  // coalesced h1 global write straight from LDS
#pragma unroll
  for (int i = 0; i < 4; ++i) {
    int u = t + i * 256;
    int row = tb + (u >> 4);
    if (row < NN)
      *(uint4*)(h1 + (size_t)tb * D + u * 8) = *(const uint4*)(abuf + swz_u(u) * 8);
  }

  // hq = h1 @ Wq1 + bq1
  stage_wh(wbuf, WTq, t);
  __syncthreads();
  f4_t aq[8] = {};
  tile16h(wbuf, hfr, l15, quad, aq);
  __syncthreads();
  stage_wh(wbuf, WTq + 64 * D, t);
  __syncthreads();
  tile16h(wbuf, hfr, l15, quad, aq + 4);
  store_c8(hq, bq1, aq, base, l15, quad, false);
  __syncthreads();

  // hk = h1 @ Wk1 + bk1
  stage_wh(wbuf, WTk, t);
  __syncthreads();
  f4_t ak[8] = {};
  tile16h(wbuf, hfr, l15, quad, ak);
  __syncthreads();
  stage_wh(wbuf, WTk + 64 * D, t);
  __syncthreads();
  tile16h(wbuf, hfr, l15, quad, ak + 4);
  store_c8(hk, bk1, ak, base, l15, quad, false);
}

// ---------------- fused: h2 = leaky(ag@Wr1 + br1) (LDS only) + JK readout ------------
__global__ __launch_bounds__(256) void wr_ro(
    const unsigned short* __restrict__ ag,
    const unsigned short* __restrict__ WTr, const float* __restrict__ brr,
    const unsigned short* __restrict__ x0,
    const unsigned short* __restrict__ h1,
    const unsigned short* __restrict__ WTro, const float* __restrict__ bro_,
    float* __restrict__ out) {
  __shared__ unsigned short wbuf[64 * D];  // 16 KB
  __shared__ unsigned short abuf[64 * D];  // 16 KB
  const int t = threadIdx.x, wave = t >> 6, lane = t & 63;
  const int l15 = lane & 15, quad = lane >> 4;
  const int tb = blockIdx.x * 64;
  const int base = tb + wave * 16;
  const size_t WM = (size_t)D * D;

  // phase 0: acch = ag @ Wr1 (two halves)
  bf8_t afr[4];
  load_a16(ag, base, l15, quad, afr);
  stage_wh(wbuf, WTr, t);
  __syncthreads();
  f4_t acch[8] = {};
  tile16h(wbuf, afr, l15, quad, acch);
  __syncthreads();
  stage_wh(wbuf, WTr + 64 * D, t);
  __syncthreads();
  tile16h(wbuf, afr, l15, quad, acch + 4);

  ACC_TO_ABUF(acch, brr);          // h2 tile -> abuf (never touches global)
  __syncthreads();

  bf8_t hfr[4];
  load_a16_lds(abuf, wave, l15, quad, hfr);
  f4_t acc[8] = {};

  // acc += h2 @ Wro2
  stage_wh(wbuf, WTro + 2 * WM, t);
  __syncthreads();
  tile16h(wbuf, hfr, l15, quad, acc);
  __syncthreads();
  stage_wh(wbuf, WTro + 2 * WM + 64 * D, t);
  __syncthreads();
  tile16h(wbuf, hfr, l15, quad, acc + 4);
  __syncthreads();

  // acc += x0 @ Wro0
  load_a16(x0, base, l15, quad, afr);
  stage_wh(wbuf, WTro, t);
  __syncthreads();
  tile16h(wbuf, afr, l15, quad, acc);
  __syncthreads();
  stage_wh(wbuf, WTro + 64 * D, t);
  __syncthreads();
  tile16h(wbuf, afr, l15, quad, acc + 4);
  __syncthreads();

  // acc += h1 @ Wro1
  load_a16(h1, base, l15, quad, afr);
  stage_wh(wbuf, WTro + WM, t);
  __syncthreads();
  tile16h(wbuf, afr, l15, quad, acc);
  __syncthreads();
  stage_wh(wbuf, WTro + WM + 64 * D, t);
  __syncthreads();
  tile16h(wbuf, afr, l15, quad, acc + 4);

#pragma unroll
  for (int j = 0; j < 8; ++j) {
    int col = (j >> 2) * 64 + (j & 3) * 16 + l15;
    float bsum = bro_[col] + bro_[D + col] + bro_[2 * D + col];
#pragma unroll
    for (int reg = 0; reg < 4; ++reg) {
      int row = base + quad * 4 + reg;
      if (row < NN) out[(size_t)row * D + col] = acc[j][reg] + bsum;
    }
  }
}

// ---------------- launch ----------------
extern "C" void kernel_launch(void* const* d_in, const int* in_sizes, int n_in,
                              void* d_out, int out_size, void* d_ws, size_t ws_size,
                              hipStream_t stream) {
  const float* feats = (const float*)d_in[0];
  const float* Wq = (const float*)d_in[1];
  const float* bq = (const float*)d_in[2];
  const float* Wk = (const float*)d_in[3];
  const float* bk = (const float*)d_in[4];
  const float* Wr = (const float*)d_in[5];
  const float* br = (const float*)d_in[6];
  const float* Wro = (const float*)d_in[7];
  const float* bro = (const float*)d_in[8];
  const int* src = (const int*)d_in[9];
  const int* dst = (const int*)d_in[10];
  float* out = (float*)d_out;

  size_t off = 0;
  char* base = (char*)d_ws;
  auto alloc = [&](size_t bytes) -> void* {
    void* p = base + off;
    off += (bytes + 255) & ~(size_t)255;
    return p;
  };
  int* H_T = (int*)alloc((size_t)NEB * NB2 * 4);
  int* btot = (int*)alloc((size_t)NB2 * 4);
  unsigned int* ebuf2 = (unsigned int*)alloc((size_t)NB2 * NEB * CAPB * 4);
  int* ssrc = (int*)alloc((size_t)NE * 4);
  int* rowptr = (int*)alloc((size_t)(NN + 1) * 4);
  int* deg = (int*)alloc((size_t)NN * 4);
  unsigned short* WT = (unsigned short*)alloc((size_t)9 * D * D * 2);
  unsigned short* x0 = (unsigned short*)alloc((size_t)NN * D * 2);
  unsigned short* hq = (unsigned short*)alloc((size_t)NN * D * 2);
  unsigned short* hk = (unsigned short*)alloc((size_t)NN * D * 2);
  unsigned short* ag = (unsigned short*)alloc((size_t)NN * D * 2);
  unsigned short* h1 = (unsigned short*)alloc((size_t)NN * D * 2);

  const size_t WM = (size_t)D * D;
  const int ab = (NN + 3) / 4;

  // 0: zero bucket totals (tiny)
  hipMemsetAsync(btot, 0, (size_t)NB2 * 4, stream);
  // 1: fused hist/scatter (edge blocks first) + weights + feats convert
  setup<<<SB_TOTAL, 256, 0, stream>>>(Wq, Wk, Wr, Wro, feats, src, dst,
                                      WT, x0, ebuf2, H_T, btot);
  // 2: per-bucket counting sort (196, cell-drain) + layer-0 merged Q&K GEMM (782)
  sort_qk0<<<NB2 + NT64, 256, 0, stream>>>(H_T, btot, ebuf2, ssrc, rowptr, deg,
                                           x0, WT + 0 * WM, bq, WT + 2 * WM, bk,
                                           hq, hk);
  // 3: layer-0 aggregate (high-TLP: one node per wave)
  aggregate<<<ab, 256, 0, stream>>>(rowptr, ssrc, deg, hq, hk, ag);
  // 4: fused h1 = leaky(ag@Wr0), hq/hk = h1@Wq1/Wk1 (single round)
  wr_qk1<<<NT64, 256, 0, stream>>>(ag, WT + 4 * WM, br, h1,
                                   WT + 1 * WM, bq + D, hq,
                                   WT + 3 * WM, bk + D, hk);
  // 5: layer-1 aggregate
  aggregate<<<ab, 256, 0, stream>>>(rowptr, ssrc, deg, hq, hk, ag);
  // 6: fused h2 = leaky(ag@Wr1) (LDS-only) + JK readout (single round)
  wr_ro<<<NT64, 256, 0, stream>>>(ag, WT + 5 * WM, br + D, x0, h1,
                                  WT + 6 * WM, bro, out);
}

// Round 9
// 255.733 us; speedup vs baseline: 1.0450x; 1.0444x over previous
//
#include <hip/hip_runtime.h>

#define NN 50000
#define NE 800000
#define D 128
#define NEG 0.2f

#define NEB 256          // edge blocks (hist+scatter) in setup
#define TILE1 3125       // NE / NEB (exact)
#define NB2 196          // coarse buckets (dst>>8)
#define CAPB 128         // per-(bucket,block) cell capacity (Poisson(16) -> safe)
#define NT64 782         // ceil(NN/64) row tiles

// setup kernel block ranges: edges FIRST (longest serial chain starts earliest)
#define SB_PREP 576              // 9 matrices x 64 blocks
#define SB_CONV 6250             // NN*D/4/256
#define SB_TOTAL (NEB + SB_PREP + SB_CONV)

typedef short bf8_t __attribute__((ext_vector_type(8)));   // 8 x bf16 (16 B)
typedef float f4_t __attribute__((ext_vector_type(4)));

__device__ __forceinline__ unsigned short f2bf(float f) {
  unsigned int u = __float_as_uint(f);
  return (unsigned short)((u + 0x7FFF + ((u >> 16) & 1)) >> 16);  // RNE
}
__device__ __forceinline__ float bf2f(unsigned int b) { return __uint_as_float(b << 16); }

__device__ __forceinline__ f4_t MF(bf8_t a, bf8_t b, f4_t c) {
  return __builtin_amdgcn_mfma_f32_16x16x32_bf16(a, b, c, 0, 0, 0);
}

// LDS tile swizzle: 16B unit u, row = u>>4 (16 units per 128-col bf16 row).
// XOR row's low 3 bits into the unit index -> ds_read_b128 at the 8-beat floor.
__device__ __forceinline__ int swz_u(int u) { return u ^ ((u >> 4) & 7); }

// exclusive scan of 256 values (one per thread); wsum = 4-int LDS scratch.
// NOTE: contains one __syncthreads; caller must sync before reusing wsum.
__device__ __forceinline__ int excl_scan256(int x, int t, int* wsum) {
  const int lane = t & 63, wave = t >> 6;
  int v = x;
#pragma unroll
  for (int off = 1; off < 64; off <<= 1) {
    int y = __shfl_up(v, off, 64);
    if (lane >= off) v += y;
  }
  if (lane == 63) wsum[wave] = v;
  __syncthreads();
  int wbase = 0;
  for (int w = 0; w < wave; ++w) wbase += wsum[w];
  return wbase + v - x;
}

// ---------------- GEMM building blocks ------------------------------------------------
// wbuf holds HALF a weight matrix (64 out-cols x 128 k = 16 KB).

__device__ __forceinline__ void stage_wh(unsigned short* wbuf,
                                         const unsigned short* __restrict__ WTh, int t) {
#pragma unroll
  for (int i = 0; i < 4; ++i) {
    int u = t + i * 256;                       // 1024 units = 64 rows x 16
    *(uint4*)(wbuf + swz_u(u) * 8) = *(const uint4*)(WTh + u * 8);
  }
}

__device__ __forceinline__ void load_a16(const unsigned short* __restrict__ A,
                                         int base, int l15, int quad, bf8_t (&afr)[4]) {
  int r = base + l15;
  if (r >= NN) r = NN - 1;
  const unsigned short* p = A + (size_t)r * D + quad * 8;
#pragma unroll
  for (int kc = 0; kc < 4; ++kc) afr[kc] = *(const bf8_t*)(p + kc * 32);
}

// A-fragments from a swizzled 64x128 LDS tile
__device__ __forceinline__ void load_a16_lds(const unsigned short* buf, int wave,
                                             int l15, int quad, bf8_t (&afr)[4]) {
  const int r = wave * 16 + l15;
#pragma unroll
  for (int kc = 0; kc < 4; ++kc)
    afr[kc] = *(const bf8_t*)(buf + swz_u(r * 16 + kc * 4 + quad) * 8);
}

// one half: 4 output n-tiles (64 cols), 16 MFMAs
__device__ __forceinline__ void tile16h(const unsigned short* wbuf, const bf8_t (&afr)[4],
                                        int l15, int quad, f4_t* acc4) {
#pragma unroll
  for (int kc = 0; kc < 4; ++kc)
#pragma unroll
    for (int nt = 0; nt < 4; ++nt) {
      bf8_t b = *(const bf8_t*)(wbuf + swz_u((nt * 16 + l15) * 16 + kc * 4 + quad) * 8);
      acc4[nt] = MF(afr[kc], b, acc4[nt]);
    }
}

// acc[j] covers col = (j>>2)*64 + (j&3)*16 + l15
__device__ __forceinline__ void store_c8(unsigned short* __restrict__ C,
                                         const float* __restrict__ bias,
                                         const f4_t (&acc)[8], int base, int l15,
                                         int quad, bool lk) {
#pragma unroll
  for (int j = 0; j < 8; ++j) {
    int col = (j >> 2) * 64 + (j & 3) * 16 + l15;
    float bb = bias[col];
#pragma unroll
    for (int reg = 0; reg < 4; ++reg) {
      int row = base + quad * 4 + reg;
      if (row < NN) {
        float v = acc[j][reg] + bb;
        if (lk) v = v >= 0.f ? v : NEG * v;
        C[(size_t)row * D + col] = f2bf(v);
      }
    }
  }
}

// write leaky(acc+bias) into abuf (swizzled), rows local to tile
#define ACC_TO_ABUF(ACC, BIAS)                                        \
  {                                                                   \
    _Pragma("unroll") for (int j = 0; j < 8; ++j) {                   \
      int col = (j >> 2) * 64 + (j & 3) * 16 + l15;                   \
      float bb = (BIAS)[col];                                         \
      _Pragma("unroll") for (int reg = 0; reg < 4; ++reg) {           \
        int rl = wave * 16 + quad * 4 + reg;                          \
        float v = ACC[j][reg] + bb;                                   \
        v = v >= 0.f ? v : NEG * v;                                   \
        int s = rl * D + col;                                         \
        abuf[s ^ ((rl & 7) << 3)] = f2bf(v);                          \
      }                                                               \
    }                                                                 \
  }

// ---------------- setup: fused hist/scatter (first) + weight prep + feats convert ----
// Edge blocks scatter directly into private cells ebuf2[bucket][blk][CAPB] using only
// a block-local LDS cursor; counts published to H_T[blk][bucket]. No global offsets.
__global__ __launch_bounds__(256) void setup(
    const float* __restrict__ Wq, const float* __restrict__ Wk,
    const float* __restrict__ Wr, const float* __restrict__ Wro,
    const float* __restrict__ feats, const int* __restrict__ src,
    const int* __restrict__ dst,
    unsigned short* __restrict__ WT, unsigned short* __restrict__ x0,
    unsigned int* __restrict__ ebuf2, int* __restrict__ H_T) {
  __shared__ int cnt[NB2];
  const int b = blockIdx.x;
  const int t = threadIdx.x;
  if (b < NEB) {
    const int blk = b;
    if (t < NB2) cnt[t] = 0;
    __syncthreads();
    const int beg = blk * TILE1, end = beg + TILE1;
    for (int i = beg + t; i < end; i += 256) {
      unsigned int d = (unsigned int)dst[i];
      unsigned int s = (unsigned int)src[i];
      int bkt = (int)(d >> 8);
      int pos = atomicAdd(&cnt[bkt], 1);
      if (pos < CAPB)
        ebuf2[((size_t)bkt * NEB + blk) * CAPB + pos] = s | (d << 16);
    }
    __syncthreads();
    if (t < NB2) H_T[blk * NB2 + t] = cnt[t];
  } else if (b < NEB + SB_PREP) {
    const int pb = b - NEB;
    const int m = pb >> 6, xb = pb & 63;
    const float* sp;
    if (m < 2) sp = Wq + m * D * D;
    else if (m < 4) sp = Wk + (m - 2) * D * D;
    else if (m < 6) sp = Wr + (m - 4) * D * D;
    else sp = Wro + (m - 6) * D * D;
    const int n = xb * 2 + (t >> 7);
    const int k = t & 127;
    WT[(size_t)m * D * D + n * D + k] = f2bf(sp[k * D + n]);
  } else {
    int i = ((b - NEB - SB_PREP) * 256 + t) * 4;
    float4 v = *(const float4*)(feats + i);
    ushort4 o = {f2bf(v.x), f2bf(v.y), f2bf(v.z), f2bf(v.w)};
    *(ushort4*)(x0 + i) = o;
  }
}

// ---------------- merged: per-bucket counting sort (196 blocks) + layer-0 Q&K GEMM ---
// Sort block b: bucket bases from H_T column sums; thread t drains cell (b, blk=t).
// GEMM blocks do BOTH Wq and Wk for their 64-row tile (x0 A-fragments loaded once).
// LDS = 16 KB -> 978 blocks co-resident in a single round.
__global__ __launch_bounds__(256) void sort_qk0(
    const int* __restrict__ H_T, const unsigned int* __restrict__ ebuf2,
    int* __restrict__ ssrc, int* __restrict__ rowptr, int* __restrict__ deg,
    const unsigned short* __restrict__ x0,
    const unsigned short* __restrict__ WTq, const float* __restrict__ bq_,
    const unsigned short* __restrict__ WTk, const float* __restrict__ bk_,
    unsigned short* __restrict__ hq, unsigned short* __restrict__ hk) {
  __shared__ __align__(16) unsigned char smraw[16384];  // GEMM 16KB / sort ~3.1KB
  const int t = threadIdx.x;
  const int gx = blockIdx.x;
  if (gx < NB2) {
    int* cnt = (int*)smraw;          // 256: per-node counts
    int* fill = cnt + 256;           // 256: per-node cursors
    int* sc = fill + 256;            // 256: bucket bases
    int* wsum = sc + 256;            // 4
    const int b = gx;
    // bucket totals (thread t = bucket t) -> exclusive scan -> bases
    int tot = 0;
    if (t < NB2)
#pragma unroll 4
      for (int j = 0; j < NEB; ++j) tot += H_T[j * NB2 + t];
    int bbase = excl_scan256(tot, t, wsum);
    sc[t] = bbase;
    __syncthreads();
    const int beg = sc[b];
    // per-cell count: thread t drains cell (bucket b, blk t)
    int cj = H_T[t * NB2 + b];
    if (cj > CAPB) cj = CAPB;
    const unsigned int* cell = ebuf2 + ((size_t)b * NEB + t) * CAPB;
    cnt[t] = 0;
    __syncthreads();
    for (int i = 0; i < cj; ++i)
      atomicAdd(&cnt[(cell[i] >> 16) & 255], 1);
    __syncthreads();
    const int x = cnt[t];
    const int excl = excl_scan256(x, t, wsum);
    fill[t] = excl;
    const int node = (b << 8) + t;
    if (node < NN) {
      rowptr[node] = beg + excl;
      deg[node] = x;
    }
    if (b == 0 && t == 0) rowptr[NN] = NE;
    __syncthreads();
    for (int i = 0; i < cj; ++i) {
      unsigned int p = cell[i];
      int pos = atomicAdd(&fill[(p >> 16) & 255], 1);
      ssrc[beg + pos] = (int)(p & 0xFFFFu);
    }
  } else {
    unsigned short* wbuf = (unsigned short*)smraw;
    const int tile = gx - NB2;
    const int wave = t >> 6, lane = t & 63;
    const int l15 = lane & 15, quad = lane >> 4;
    const int base = tile * 64 + wave * 16;
    bf8_t afr[4];
    load_a16(x0, base, l15, quad, afr);
    // Q
    stage_wh(wbuf, WTq, t);
    __syncthreads();
    f4_t aq[8] = {};
    tile16h(wbuf, afr, l15, quad, aq);
    __syncthreads();
    stage_wh(wbuf, WTq + 64 * D, t);
    __syncthreads();
    tile16h(wbuf, afr, l15, quad, aq + 4);
    store_c8(hq, bq_, aq, base, l15, quad, false);
    __syncthreads();
    // K
    stage_wh(wbuf, WTk, t);
    __syncthreads();
    f4_t ak[8] = {};
    tile16h(wbuf, afr, l15, quad, ak);
    __syncthreads();
    stage_wh(wbuf, WTk + 64 * D, t);
    __syncthreads();
    tile16h(wbuf, afr, l15, quad, ak + 4);
    store_c8(hk, bk_, ak, base, l15, quad, false);
  }
}

// ---------------- aggregation: high-TLP gather, one node per wave --------------------
#define PROC(kb)                                                     \
  {                                                                  \
    float m;                                                         \
    m = q[0] + bf2f(kb.x & 0xFFFFu); a[0] += m >= 0.f ? m : NEG * m; \
    m = q[1] + bf2f(kb.x >> 16);     a[1] += m >= 0.f ? m : NEG * m; \
    m = q[2] + bf2f(kb.y & 0xFFFFu); a[2] += m >= 0.f ? m : NEG * m; \
    m = q[3] + bf2f(kb.y >> 16);     a[3] += m >= 0.f ? m : NEG * m; \
    m = q[4] + bf2f(kb.z & 0xFFFFu); a[4] += m >= 0.f ? m : NEG * m; \
    m = q[5] + bf2f(kb.z >> 16);     a[5] += m >= 0.f ? m : NEG * m; \
    m = q[6] + bf2f(kb.w & 0xFFFFu); a[6] += m >= 0.f ? m : NEG * m; \
    m = q[7] + bf2f(kb.w >> 16);     a[7] += m >= 0.f ? m : NEG * m; \
  }

__global__ __launch_bounds__(256) void aggregate(
    const int* __restrict__ rowptr, const int* __restrict__ ssrc,
    const int* __restrict__ deg,
    const unsigned short* __restrict__ hq, const unsigned short* __restrict__ hk,
    unsigned short* __restrict__ ag) {
  const int wave = threadIdx.x >> 6, lane = threadIdx.x & 63;
  const int v = blockIdx.x * 4 + wave;
  if (v >= NN) return;
  const int sub = lane & 15, grp = lane >> 4;
  const int beg = rowptr[v], end = rowptr[v + 1];

  uint4 qb = *(const uint4*)(hq + (size_t)v * D + sub * 8);
  float q[8];
  q[0] = bf2f(qb.x & 0xFFFFu); q[1] = bf2f(qb.x >> 16);
  q[2] = bf2f(qb.y & 0xFFFFu); q[3] = bf2f(qb.y >> 16);
  q[4] = bf2f(qb.z & 0xFFFFu); q[5] = bf2f(qb.z >> 16);
  q[6] = bf2f(qb.w & 0xFFFFu); q[7] = bf2f(qb.w >> 16);

  float a[8] = {0.f, 0.f, 0.f, 0.f, 0.f, 0.f, 0.f, 0.f};
  int e = beg + grp;
  for (; e + 12 < end; e += 16) {  // 4 edge streams -> 16 x 16B in flight per wave
    int s0 = ssrc[e];
    int s1 = ssrc[e + 4];
    int s2 = ssrc[e + 8];
    int s3 = ssrc[e + 12];
    uint4 k0 = *(const uint4*)(hk + (size_t)s0 * D + sub * 8);
    uint4 k1 = *(const uint4*)(hk + (size_t)s1 * D + sub * 8);
    uint4 k2 = *(const uint4*)(hk + (size_t)s2 * D + sub * 8);
    uint4 k3 = *(const uint4*)(hk + (size_t)s3 * D + sub * 8);
    PROC(k0);
    PROC(k1);
    PROC(k2);
    PROC(k3);
  }
  for (; e + 4 < end; e += 8) {    // pair tail
    int s0 = ssrc[e];
    int s1 = ssrc[e + 4];
    uint4 k0 = *(const uint4*)(hk + (size_t)s0 * D + sub * 8);
    uint4 k1 = *(const uint4*)(hk + (size_t)s1 * D + sub * 8);
    PROC(k0);
    PROC(k1);
  }
  if (e < end) {
    int s0 = ssrc[e];
    uint4 k0 = *(const uint4*)(hk + (size_t)s0 * D + sub * 8);
    PROC(k0);
  }
#pragma unroll
  for (int j = 0; j < 8; ++j) {
    a[j] += __shfl_xor(a[j], 16, 64);
    a[j] += __shfl_xor(a[j], 32, 64);
  }
  if (grp == 0) {
    float inv = 1.f / fmaxf((float)deg[v], 1.f);
    uint4 o;
    o.x = (unsigned int)f2bf(a[0] * inv) | ((unsigned int)f2bf(a[1] * inv) << 16);
    o.y = (unsigned int)f2bf(a[2] * inv) | ((unsigned int)f2bf(a[3] * inv) << 16);
    o.z = (unsigned int)f2bf(a[4] * inv) | ((unsigned int)f2bf(a[5] * inv) << 16);
    o.w = (unsigned int)f2bf(a[6] * inv) | ((unsigned int)f2bf(a[7] * inv) << 16);
    *(uint4*)(ag + (size_t)v * D + sub * 8) = o;
  }
}

// ---------------- fused: h1 = leaky(ag@Wr0 + br0); hq = h1@Wq1; hk = h1@Wk1 ----------
// 32 KB LDS -> 5 blocks/CU -> 782 blocks in a single residency round.
__global__ __launch_bounds__(256) void wr_qk1(
    const unsigned short* __restrict__ ag,
    const unsigned short* __restrict__ WTr, const float* __restrict__ brr,
    unsigned short* __restrict__ h1,
    const unsigned short* __restrict__ WTq, const float* __restrict__ bq1,
    unsigned short* __restrict__ hq,
    const unsigned short* __restrict__ WTk, const float* __restrict__ bk1,
    unsigned short* __restrict__ hk) {
  __shared__ unsigned short wbuf[64 * D];  // 16 KB (half weight)
  __shared__ unsigned short abuf[64 * D];  // 16 KB (swizzled h1 tile)
  const int t = threadIdx.x, wave = t >> 6, lane = t & 63;
  const int l15 = lane & 15, quad = lane >> 4;
  const int tb = blockIdx.x * 64;
  const int base = tb + wave * 16;

  // phase 0: acc = ag @ Wr0 (two halves)
  bf8_t afr[4];
  load_a16(ag, base, l15, quad, afr);
  stage_wh(wbuf, WTr, t);
  __syncthreads();
  f4_t acc[8] = {};
  tile16h(wbuf, afr, l15, quad, acc);
  __syncthreads();
  stage_wh(wbuf, WTr + 64 * D, t);
  __syncthreads();
  tile16h(wbuf, afr, l15, quad, acc + 4);

  ACC_TO_ABUF(acc, brr);           // h1 tile -> abuf (own elements, no hazard)
  __syncthreads();

  bf8_t hfr[4];
  load_a16_lds(abuf, wave, l15, quad, hfr);
  // coalesced h1 global write straight from LDS
#pragma unroll
  for (int i = 0; i < 4; ++i) {
    int u = t + i * 256;
    int row = tb + (u >> 4);
    if (row < NN)
      *(uint4*)(h1 + (size_t)tb * D + u * 8) = *(const uint4*)(abuf + swz_u(u) * 8);
  }

  // hq = h1 @ Wq1 + bq1
  stage_wh(wbuf, WTq, t);
  __syncthreads();
  f4_t aq[8] = {};
  tile16h(wbuf, hfr, l15, quad, aq);
  __syncthreads();
  stage_wh(wbuf, WTq + 64 * D, t);
  __syncthreads();
  tile16h(wbuf, hfr, l15, quad, aq + 4);
  store_c8(hq, bq1, aq, base, l15, quad, false);
  __syncthreads();

  // hk = h1 @ Wk1 + bk1
  stage_wh(wbuf, WTk, t);
  __syncthreads();
  f4_t ak[8] = {};
  tile16h(wbuf, hfr, l15, quad, ak);
  __syncthreads();
  stage_wh(wbuf, WTk + 64 * D, t);
  __syncthreads();
  tile16h(wbuf, hfr, l15, quad, ak + 4);
  store_c8(hk, bk1, ak, base, l15, quad, false);
}

// ---------------- fused: h2 = leaky(ag@Wr1 + br1) (LDS only) + JK readout ------------
__global__ __launch_bounds__(256) void wr_ro(
    const unsigned short* __restrict__ ag,
    const unsigned short* __restrict__ WTr, const float* __restrict__ brr,
    const unsigned short* __restrict__ x0,
    const unsigned short* __restrict__ h1,
    const unsigned short* __restrict__ WTro, const float* __restrict__ bro_,
    float* __restrict__ out) {
  __shared__ unsigned short wbuf[64 * D];  // 16 KB
  __shared__ unsigned short abuf[64 * D];  // 16 KB
  const int t = threadIdx.x, wave = t >> 6, lane = t & 63;
  const int l15 = lane & 15, quad = lane >> 4;
  const int tb = blockIdx.x * 64;
  const int base = tb + wave * 16;
  const size_t WM = (size_t)D * D;

  // phase 0: acch = ag @ Wr1 (two halves)
  bf8_t afr[4];
  load_a16(ag, base, l15, quad, afr);
  stage_wh(wbuf, WTr, t);
  __syncthreads();
  f4_t acch[8] = {};
  tile16h(wbuf, afr, l15, quad, acch);
  __syncthreads();
  stage_wh(wbuf, WTr + 64 * D, t);
  __syncthreads();
  tile16h(wbuf, afr, l15, quad, acch + 4);

  ACC_TO_ABUF(acch, brr);          // h2 tile -> abuf (never touches global)
  __syncthreads();

  bf8_t hfr[4];
  load_a16_lds(abuf, wave, l15, quad, hfr);
  f4_t acc[8] = {};

  // acc += h2 @ Wro2
  stage_wh(wbuf, WTro + 2 * WM, t);
  __syncthreads();
  tile16h(wbuf, hfr, l15, quad, acc);
  __syncthreads();
  stage_wh(wbuf, WTro + 2 * WM + 64 * D, t);
  __syncthreads();
  tile16h(wbuf, hfr, l15, quad, acc + 4);
  __syncthreads();

  // acc += x0 @ Wro0
  load_a16(x0, base, l15, quad, afr);
  stage_wh(wbuf, WTro, t);
  __syncthreads();
  tile16h(wbuf, afr, l15, quad, acc);
  __syncthreads();
  stage_wh(wbuf, WTro + 64 * D, t);
  __syncthreads();
  tile16h(wbuf, afr, l15, quad, acc + 4);
  __syncthreads();

  // acc += h1 @ Wro1
  load_a16(h1, base, l15, quad, afr);
  stage_wh(wbuf, WTro + WM, t);
  __syncthreads();
  tile16h(wbuf, afr, l15, quad, acc);
  __syncthreads();
  stage_wh(wbuf, WTro + WM + 64 * D, t);
  __syncthreads();
  tile16h(wbuf, afr, l15, quad, acc + 4);

#pragma unroll
  for (int j = 0; j < 8; ++j) {
    int col = (j >> 2) * 64 + (j & 3) * 16 + l15;
    float bsum = bro_[col] + bro_[D + col] + bro_[2 * D + col];
#pragma unroll
    for (int reg = 0; reg < 4; ++reg) {
      int row = base + quad * 4 + reg;
      if (row < NN) out[(size_t)row * D + col] = acc[j][reg] + bsum;
    }
  }
}

// ---------------- launch ----------------
extern "C" void kernel_launch(void* const* d_in, const int* in_sizes, int n_in,
                              void* d_out, int out_size, void* d_ws, size_t ws_size,
                              hipStream_t stream) {
  const float* feats = (const float*)d_in[0];
  const float* Wq = (const float*)d_in[1];
  const float* bq = (const float*)d_in[2];
  const float* Wk = (const float*)d_in[3];
  const float* bk = (const float*)d_in[4];
  const float* Wr = (const float*)d_in[5];
  const float* br = (const float*)d_in[6];
  const float* Wro = (const float*)d_in[7];
  const float* bro = (const float*)d_in[8];
  const int* src = (const int*)d_in[9];
  const int* dst = (const int*)d_in[10];
  float* out = (float*)d_out;

  size_t off = 0;
  char* base = (char*)d_ws;
  auto alloc = [&](size_t bytes) -> void* {
    void* p = base + off;
    off += (bytes + 255) & ~(size_t)255;
    return p;
  };
  int* H_T = (int*)alloc((size_t)NEB * NB2 * 4);
  unsigned int* ebuf2 = (unsigned int*)alloc((size_t)NB2 * NEB * CAPB * 4);
  int* ssrc = (int*)alloc((size_t)NE * 4);
  int* rowptr = (int*)alloc((size_t)(NN + 1) * 4);
  int* deg = (int*)alloc((size_t)NN * 4);
  unsigned short* WT = (unsigned short*)alloc((size_t)9 * D * D * 2);
  unsigned short* x0 = (unsigned short*)alloc((size_t)NN * D * 2);
  unsigned short* hq = (unsigned short*)alloc((size_t)NN * D * 2);
  unsigned short* hk = (unsigned short*)alloc((size_t)NN * D * 2);
  unsigned short* ag = (unsigned short*)alloc((size_t)NN * D * 2);
  unsigned short* h1 = (unsigned short*)alloc((size_t)NN * D * 2);

  const size_t WM = (size_t)D * D;
  const int ab = (NN + 3) / 4;

  // 1: fused hist/scatter (edge blocks first) + weights + feats convert
  setup<<<SB_TOTAL, 256, 0, stream>>>(Wq, Wk, Wr, Wro, feats, src, dst,
                                      WT, x0, ebuf2, H_T);
  // 2: per-bucket counting sort (196, cell-drain) + layer-0 merged Q&K GEMM (782)
  sort_qk0<<<NB2 + NT64, 256, 0, stream>>>(H_T, ebuf2, ssrc, rowptr, deg,
                                           x0, WT + 0 * WM, bq, WT + 2 * WM, bk,
                                           hq, hk);
  // 3: layer-0 aggregate (high-TLP: one node per wave)
  aggregate<<<ab, 256, 0, stream>>>(rowptr, ssrc, deg, hq, hk, ag);
  // 4: fused h1 = leaky(ag@Wr0), hq/hk = h1@Wq1/Wk1 (single round)
  wr_qk1<<<NT64, 256, 0, stream>>>(ag, WT + 4 * WM, br, h1,
                                   WT + 1 * WM, bq + D, hq,
                                   WT + 3 * WM, bk + D, hk);
  // 5: layer-1 aggregate
  aggregate<<<ab, 256, 0, stream>>>(rowptr, ssrc, deg, hq, hk, ag);
  // 6: fused h2 = leaky(ag@Wr1) (LDS-only) + JK readout (single round)
  wr_ro<<<NT64, 256, 0, stream>>>(ag, WT + 5 * WM, br + D, x0, h1,
                                  WT + 6 * WM, bro, out);
}